// Round 6
// baseline (689.431 us; speedup 1.0000x reference)
//
#include <hip/hip_runtime.h>

// ---------- types ----------
typedef short short8 __attribute__((ext_vector_type(8)));
typedef unsigned short ushort8 __attribute__((ext_vector_type(8)));
typedef float float4v __attribute__((ext_vector_type(4)));

// ---------- bf16 helpers (bit-level) ----------
__device__ __forceinline__ unsigned short f2bf(float f) {
    union { float f; unsigned u; } v; v.f = f;
    unsigned r = v.u + 0x7fffu + ((v.u >> 16) & 1u);   // RNE
    return (unsigned short)(r >> 16);
}

// ---------- fp32 -> bf16 cast (vectorized) ----------
__global__ __launch_bounds__(256) void cast_bf16_kernel(
        const float* __restrict__ in, unsigned short* __restrict__ out, int n) {
    int i4 = (blockIdx.x * 256 + threadIdx.x) * 4;
    if (i4 < n) {
        float4 f = *(const float4*)(in + i4);
        ushort4 u;
        u.x = f2bf(f.x); u.y = f2bf(f.y); u.z = f2bf(f.z); u.w = f2bf(f.w);
        *(ushort4*)(out + i4) = u;
    }
}

// encoder cast with per-batch row padding 77 -> 96  ([4,77,2048] -> [4,96,2048])
__global__ __launch_bounds__(256) void cast_enc_pad_kernel(
        const float* __restrict__ in, unsigned short* __restrict__ out) {
    int i4 = blockIdx.x * 256 + threadIdx.x;         // float4 index
    if (i4 < 4 * 77 * 2048 / 4) {
        const int per_b = 77 * 2048 / 4;             // 39424
        int b = i4 / per_b;
        int rem = i4 - b * per_b;
        float4 f = *(const float4*)(in + (size_t)i4 * 4);
        ushort4 u;
        u.x = f2bf(f.x); u.y = f2bf(f.y); u.z = f2bf(f.z); u.w = f2bf(f.w);
        *(ushort4*)(out + ((size_t)b * (96 * 2048 / 4) + rem) * 4) = u;
    }
}

// ---------- bf16 GEMM core, C[m,n] = sum_k A[m,k]*B[n,k] ----------
// 128x128 tile, BK=64, register-prefetch pipeline:
//   load tile k+1 -> VGPRs (issue)  |  MFMA on tile k from LDS  |  barrier
//   ds_write staged regs (data-dep vmcnt wait lands on ~arrived loads) | barrier
// R5 evidence: global_load_lds + immediate barrier exposed full HBM latency
// every iter (MfmaUtil 20%, dur 109us vs 22.5us MFMA floor).
// AF32/BF32: source dtype fp32 (converted in-register) vs bf16 — lets GEMMs
// read hs/weights fp32 directly, killing the standalone cast passes.
// LDS XOR swizzle: phys chunk = logical ^ (row&7), conflict-free (R5: 0 cnf).
// EPI: 0 = fp32 out, 1 = bf16 out, 2 = fp32 out + bias[col] + resid[row*N+col]
template<int EPI, int AF32, int BF32>
__device__ __forceinline__ void gemm_core(
        const unsigned short* __restrict__ A16, const float* __restrict__ A32,
        const unsigned short* __restrict__ B16, const float* __restrict__ B32,
        float* __restrict__ Cf, unsigned short* __restrict__ Cb,
        const float* __restrict__ bias, const float* __restrict__ resid,
        int Mclamp, int N, int K, int bm, int bn) {
    __shared__ unsigned short As[128 * 64];   // 16 KB
    __shared__ unsigned short Bs[128 * 64];   // 16 KB

    const int tid  = threadIdx.x;
    const int lane = tid & 63;
    const int wave = tid >> 6;
    const int wm   = (wave >> 1) * 64;
    const int wn   = (wave & 1) * 64;
    const int lr   = lane & 15;
    const int lq   = lane >> 4;

    float4v acc[4][4] = {};

    // staging geometry: linear = r*256+tid -> row = linear>>3, logical chunk = linear&7
    const unsigned short* a16p[4]; const float* a32p[4];
    const unsigned short* b16p[4]; const float* b32p[4];
    int ldsOff[4];
    #pragma unroll
    for (int r = 0; r < 4; ++r) {
        const int linear = r * 256 + tid;
        const int row = linear >> 3;
        const int c = linear & 7;
        ldsOff[r] = row * 64 + (c ^ (row & 7)) * 8;   // swizzled dest (shorts)
        int ar = bm + row; if (ar >= Mclamp) ar = Mclamp - 1;
        if (AF32) a32p[r] = A32 + (size_t)ar * K + c * 8;
        else      a16p[r] = A16 + (size_t)ar * K + c * 8;
        if (BF32) b32p[r] = B32 + (size_t)(bn + row) * K + c * 8;
        else      b16p[r] = B16 + (size_t)(bn + row) * K + c * 8;
    }

    short8 a16r[4], b16r[4];
    float4 a32r[4][2], b32r[4][2];

    auto load_tiles = [&](int ks) {
        #pragma unroll
        for (int r = 0; r < 4; ++r) {
            if (AF32) {
                const float4* p = (const float4*)(a32p[r] + ks);
                a32r[r][0] = p[0]; a32r[r][1] = p[1];
            } else {
                a16r[r] = *(const short8*)(a16p[r] + ks);
            }
        }
        #pragma unroll
        for (int r = 0; r < 4; ++r) {
            if (BF32) {
                const float4* p = (const float4*)(b32p[r] + ks);
                b32r[r][0] = p[0]; b32r[r][1] = p[1];
            } else {
                b16r[r] = *(const short8*)(b16p[r] + ks);
            }
        }
    };
    auto store_tiles = [&]() {
        #pragma unroll
        for (int r = 0; r < 4; ++r) {
            short8 v;
            if (AF32) {
                v[0] = (short)f2bf(a32r[r][0].x); v[1] = (short)f2bf(a32r[r][0].y);
                v[2] = (short)f2bf(a32r[r][0].z); v[3] = (short)f2bf(a32r[r][0].w);
                v[4] = (short)f2bf(a32r[r][1].x); v[5] = (short)f2bf(a32r[r][1].y);
                v[6] = (short)f2bf(a32r[r][1].z); v[7] = (short)f2bf(a32r[r][1].w);
            } else v = a16r[r];
            *(short8*)(As + ldsOff[r]) = v;
        }
        #pragma unroll
        for (int r = 0; r < 4; ++r) {
            short8 v;
            if (BF32) {
                v[0] = (short)f2bf(b32r[r][0].x); v[1] = (short)f2bf(b32r[r][0].y);
                v[2] = (short)f2bf(b32r[r][0].z); v[3] = (short)f2bf(b32r[r][0].w);
                v[4] = (short)f2bf(b32r[r][1].x); v[5] = (short)f2bf(b32r[r][1].y);
                v[6] = (short)f2bf(b32r[r][1].z); v[7] = (short)f2bf(b32r[r][1].w);
            } else v = b16r[r];
            *(short8*)(Bs + ldsOff[r]) = v;
        }
    };
    auto mfma_phase = [&]() {
        #pragma unroll
        for (int kw = 0; kw < 2; ++kw) {
            short8 af[4], bfr[4];
            #pragma unroll
            for (int i = 0; i < 4; ++i) {
                const int row = wm + i * 16 + lr;
                af[i] = *(const short8*)(As + row * 64 + (((kw << 2) | lq) ^ (row & 7)) * 8);
            }
            #pragma unroll
            for (int j = 0; j < 4; ++j) {
                const int row = wn + j * 16 + lr;
                bfr[j] = *(const short8*)(Bs + row * 64 + (((kw << 2) | lq) ^ (row & 7)) * 8);
            }
            #pragma unroll
            for (int i = 0; i < 4; ++i)
                #pragma unroll
                for (int j = 0; j < 4; ++j)
                    acc[i][j] = __builtin_amdgcn_mfma_f32_16x16x32_bf16(
                                    af[i], bfr[j], acc[i][j], 0, 0, 0);
        }
    };

    // prologue: tile 0
    load_tiles(0);
    store_tiles();
    __syncthreads();
    // pipelined K-loop
    for (int ks = 64; ks < K; ks += 64) {
        load_tiles(ks);     // issue next tile's loads
        mfma_phase();       // compute current tile (hides load latency)
        __syncthreads();    // all waves done reading LDS
        store_tiles();      // vmcnt wait here — loads had a full MFMA phase
        __syncthreads();
    }
    mfma_phase();

    // C/D layout: col=lane&15, row=(lane>>4)*4+reg   [m89-verified]
    #pragma unroll
    for (int i = 0; i < 4; ++i) {
        #pragma unroll
        for (int r = 0; r < 4; ++r) {
            const int row = bm + wm + i * 16 + lq * 4 + r;
            const size_t base = (size_t)row * N;
            #pragma unroll
            for (int j = 0; j < 4; ++j) {
                const int col = bn + wn + j * 16 + lr;
                const float v = acc[i][j][r];
                const size_t idx = base + col;
                if (EPI == 2)      Cf[idx] = v + bias[col] + resid[idx];
                else if (EPI == 1) Cb[idx] = f2bf(v);
                else               Cf[idx] = v;
            }
        }
    }
}

// Q-proj: A=hs fp32, B=Wq fp32 -> bf16 out
__global__ __launch_bounds__(256) void gemm_qproj_kernel(
        const float* __restrict__ A32, const float* __restrict__ B32,
        unsigned short* __restrict__ Cb, int Mclamp, int N, int K) {
    gemm_core<1, 1, 1>(nullptr, A32, nullptr, B32, nullptr, Cb, nullptr, nullptr,
                       Mclamp, N, K, blockIdx.x * 128, blockIdx.y * 128);
}

// out-proj: A=combined bf16, B=Wo fp32 -> fp32 out + bias + resid
__global__ __launch_bounds__(256) void gemm_oproj_kernel(
        const unsigned short* __restrict__ A16, const float* __restrict__ B32,
        float* __restrict__ Cf, const float* __restrict__ bias,
        const float* __restrict__ resid, int Mclamp, int N, int K) {
    gemm_core<2, 0, 1>(A16, nullptr, nullptr, B32, Cf, nullptr, bias, resid,
                       Mclamp, N, K, blockIdx.x * 128, blockIdx.y * 128);
}

// K/V/iK/iV projections: A bf16 (padded enc / id), B fp32 weights -> bf16 out
__global__ __launch_bounds__(256) void gemm_kv4_kernel(
        const unsigned short* __restrict__ Aenc,   // [384,2048] per-batch padded
        const unsigned short* __restrict__ Aid,    // [128,2048]
        const float* __restrict__ Wk, const float* __restrict__ Wv,
        const float* __restrict__ Wik, const float* __restrict__ Wiv,
        unsigned short* __restrict__ Kb, unsigned short* __restrict__ Vb,
        unsigned short* __restrict__ IKb, unsigned short* __restrict__ IVb,
        int N, int K) {
    const int z = blockIdx.z;
    const int bm = blockIdx.x * 128;
    const int Mrows = (z < 2) ? 384 : 128;
    if (bm >= Mrows) return;
    const unsigned short* A = (z < 2) ? Aenc : Aid;
    const float* B = (z == 0) ? Wk : (z == 1) ? Wv : (z == 2) ? Wik : Wiv;
    unsigned short* C = (z == 0) ? Kb : (z == 1) ? Vb : (z == 2) ? IKb : IVb;
    gemm_core<1, 0, 1>(A, nullptr, nullptr, B, nullptr, C, nullptr, nullptr,
                       Mrows, N, K, bm, blockIdx.y * 128);
}

// ---------- MFMA fused dual attention ----------
// Block = 64 Q-rows x one (b,h); 4 waves x 16 Q-rows each.
// Accumulators are MFMA C/D fragments => AGPR-resident (R1/R3 lesson: scalar
// fp32 accumulator arrays spill to AGPR-shuffles or scratch).
#define VT_STRIDE 136
__global__ __launch_bounds__(256) void attn_mfma_kernel(
        const unsigned short* __restrict__ Q,     // [16384,1280] bf16
        const unsigned short* __restrict__ Kb,    // [384,1280]  bf16, rows b*96+t
        const unsigned short* __restrict__ Vb,    // [384,1280]  bf16
        const unsigned short* __restrict__ IKb,   // [128,1280]  bf16, rows b*32+t
        const unsigned short* __restrict__ IVb,   // [128,1280]  bf16
        unsigned short* __restrict__ Cmb) {       // [16384,1280] bf16
    const int b = blockIdx.z;
    const int h = blockIdx.y;
    const int hoff = h * 64;
    const int qbase = blockIdx.x * 64;
    const int tid = threadIdx.x;
    const int lane = tid & 63;
    const int wave = tid >> 6;
    const int l15 = lane & 15;
    const int quad = lane >> 4;

    __shared__ unsigned short Vt[64 * VT_STRIDE];  // [d][key] cross 0..95, id 96..127
    __shared__ unsigned short Pl[64 * VT_STRIDE];  // [qrow][key]

    for (int i = tid; i < 96 * 8; i += 256) {
        const int c = i / 96;
        const int key = i - c * 96;
        short8 v = *(const short8*)(Vb + (size_t)(b * 96 + key) * 1280 + hoff + c * 8);
        #pragma unroll
        for (int j = 0; j < 8; ++j)
            Vt[(c * 8 + j) * VT_STRIDE + key] = (unsigned short)v[j];
    }
    {
        const int c = tid >> 5;
        const int key = tid & 31;
        short8 v = *(const short8*)(IVb + (size_t)(b * 32 + key) * 1280 + hoff + c * 8);
        #pragma unroll
        for (int j = 0; j < 8; ++j)
            Vt[(c * 8 + j) * VT_STRIDE + 96 + key] = (unsigned short)v[j];
    }
    __syncthreads();

    const int qrow = b * 4096 + qbase + wave * 16 + l15;
    const unsigned short* qp = Q + (size_t)qrow * 1280 + hoff + quad * 8;
    const short8 aQ0 = *(const short8*)(qp);
    const short8 aQ1 = *(const short8*)(qp + 32);

    const float scale = 0.125f;
    float lC[4] = {0.f, 0.f, 0.f, 0.f};
    float lI[4] = {0.f, 0.f, 0.f, 0.f};

    #pragma unroll
    for (int t = 0; t < 5; ++t) {
        const unsigned short* kp = Kb + (size_t)(b * 96 + t * 16 + l15) * 1280 + hoff + quad * 8;
        const short8 bK0 = *(const short8*)(kp);
        const short8 bK1 = *(const short8*)(kp + 32);
        float4v s = {};
        s = __builtin_amdgcn_mfma_f32_16x16x32_bf16(aQ0, bK0, s, 0, 0, 0);
        s = __builtin_amdgcn_mfma_f32_16x16x32_bf16(aQ1, bK1, s, 0, 0, 0);
        #pragma unroll
        for (int r = 0; r < 4; ++r) {
            float p = __expf(s[r] * scale);
            if (t == 4 && l15 >= 13) p = 0.f;   // keys 77..79 masked
            lC[r] += p;
            Pl[(wave * 16 + quad * 4 + r) * VT_STRIDE + t * 16 + l15] = f2bf(p);
        }
    }
    #pragma unroll
    for (int r = 0; r < 4; ++r)
        Pl[(wave * 16 + quad * 4 + r) * VT_STRIDE + 80 + l15] = 0;

    #pragma unroll
    for (int t = 0; t < 2; ++t) {
        const unsigned short* kp = IKb + (size_t)(b * 32 + t * 16 + l15) * 1280 + hoff + quad * 8;
        const short8 bK0 = *(const short8*)(kp);
        const short8 bK1 = *(const short8*)(kp + 32);
        float4v s = {};
        s = __builtin_amdgcn_mfma_f32_16x16x32_bf16(aQ0, bK0, s, 0, 0, 0);
        s = __builtin_amdgcn_mfma_f32_16x16x32_bf16(aQ1, bK1, s, 0, 0, 0);
        #pragma unroll
        for (int r = 0; r < 4; ++r) {
            const float p = __expf(s[r] * scale);
            lI[r] += p;
            Pl[(wave * 16 + quad * 4 + r) * VT_STRIDE + 96 + t * 16 + l15] = f2bf(p);
        }
    }

    #pragma unroll
    for (int m = 1; m <= 8; m <<= 1) {
        #pragma unroll
        for (int r = 0; r < 4; ++r) {
            lC[r] += __shfl_xor(lC[r], m);
            lI[r] += __shfl_xor(lI[r], m);
        }
    }
    __syncthreads();

    float4v oC[4] = {};
    float4v oI[4] = {};
    #pragma unroll
    for (int kt = 0; kt < 3; ++kt) {
        const short8 aP = *(const short8*)(Pl + (wave * 16 + l15) * VT_STRIDE + kt * 32 + quad * 8);
        #pragma unroll
        for (int td = 0; td < 4; ++td) {
            const short8 bV = *(const short8*)(Vt + (td * 16 + l15) * VT_STRIDE + kt * 32 + quad * 8);
            oC[td] = __builtin_amdgcn_mfma_f32_16x16x32_bf16(aP, bV, oC[td], 0, 0, 0);
        }
    }
    {
        const short8 aP = *(const short8*)(Pl + (wave * 16 + l15) * VT_STRIDE + 96 + quad * 8);
        #pragma unroll
        for (int td = 0; td < 4; ++td) {
            const short8 bV = *(const short8*)(Vt + (td * 16 + l15) * VT_STRIDE + 96 + quad * 8);
            oI[td] = __builtin_amdgcn_mfma_f32_16x16x32_bf16(aP, bV, oI[td], 0, 0, 0);
        }
    }

    float rc[4], ri[4];
    #pragma unroll
    for (int r = 0; r < 4; ++r) { rc[r] = 1.f / lC[r]; ri[r] = 1.f / lI[r]; }

    #pragma unroll
    for (int td = 0; td < 4; ++td) {
        #pragma unroll
        for (int r = 0; r < 4; ++r) {
            const int row = b * 4096 + qbase + wave * 16 + quad * 4 + r;
            const int col = hoff + td * 16 + l15;
            Cmb[(size_t)row * 1280 + col] = f2bf(oC[td][r] * rc[r] + oI[td][r] * ri[r]);
        }
    }
}

// ---------- host launch ----------
extern "C" void kernel_launch(void* const* d_in, const int* in_sizes, int n_in,
                              void* d_out, int out_size, void* d_ws, size_t ws_size,
                              hipStream_t stream) {
    const float* hs  = (const float*)d_in[0];   // [4,4096,1280]
    const float* enc = (const float*)d_in[1];   // [4,77,2048]
    const float* idm = (const float*)d_in[2];   // [4,32,2048]
    const float* Wq  = (const float*)d_in[3];
    const float* Wk  = (const float*)d_in[4];
    const float* Wv  = (const float*)d_in[5];
    const float* Wik = (const float*)d_in[6];
    const float* Wiv = (const float*)d_in[7];
    const float* Wo  = (const float*)d_in[8];
    const float* bo  = (const float*)d_in[9];
    float* out = (float*)d_out;

    char* ws = (char*)d_ws;
    size_t off = 0;
    auto carve = [&](size_t bytes) {
        char* p = ws + off;
        off += (bytes + 255) & ~(size_t)255;
        return p;
    };

    unsigned short* Xh   = (unsigned short*)carve(16384ULL * 1280 * 2); // 'combined'
    unsigned short* Encb = (unsigned short*)carve(384ULL * 2048 * 2);   // per-batch padded 96 rows
    unsigned short* Idb  = (unsigned short*)carve(128ULL * 2048 * 2);
    unsigned short* Qb   = (unsigned short*)carve(16384ULL * 1280 * 2);
    unsigned short* Kb   = (unsigned short*)carve(384ULL * 1280 * 2);
    unsigned short* Vb   = (unsigned short*)carve(384ULL * 1280 * 2);
    unsigned short* IKb  = (unsigned short*)carve(128ULL * 1280 * 2);
    unsigned short* IVb  = (unsigned short*)carve(128ULL * 1280 * 2);
    (void)ws_size; (void)in_sizes; (void)n_in; (void)out_size;

    // tiny input casts (enc padded to 96 rows/batch, id)
    cast_enc_pad_kernel<<<(4 * 77 * 2048 / 4 + 255) / 256, 256, 0, stream>>>(enc, Encb);
    cast_bf16_kernel<<<(4 * 32 * 2048 / 4 + 255) / 256, 256, 0, stream>>>(
        idm, Idb, 4 * 32 * 2048);

    // Q = hs @ Wq^T -> bf16 (fp32 sources read directly)
    gemm_qproj_kernel<<<dim3(128, 10), 256, 0, stream>>>(
        hs, Wq, Qb, 16384, 1280, 1280);

    // K/V/iK/iV projections (A bf16, B fp32 weights) -> bf16
    gemm_kv4_kernel<<<dim3(3, 10, 4), 256, 0, stream>>>(
        Encb, Idb, Wk, Wv, Wik, Wiv, Kb, Vb, IKb, IVb, 1280, 2048);

    // fused MFMA attention -> combined (Xh)
    attn_mfma_kernel<<<dim3(64, 20, 4), 256, 0, stream>>>(Qb, Kb, Vb, IKb, IVb, Xh);

    // out = combined @ Wo^T + bo + residual (Wo fp32 read directly)
    gemm_oproj_kernel<<<dim3(128, 10), 256, 0, stream>>>(
        Xh, Wo, out, bo, hs, 16384, 1280, 1280);
}